// Round 1
// baseline (71.933 us; speedup 1.0000x reference)
//
#include <hip/hip_runtime.h>

#define BB 32
#define NN 1024
#define MM 1024
#define DD 128

typedef __attribute__((ext_vector_type(4))) float f32x4;
typedef __attribute__((ext_vector_type(8))) __bf16 bf16x8;
typedef unsigned short ushort_t;

__device__ __forceinline__ unsigned f2bf(float x) {
    unsigned u = __builtin_bit_cast(unsigned, x);
    return (u + 0x7fffu + ((u >> 16) & 1u)) >> 16;  // RNE bf16, finite inputs
}
__device__ __forceinline__ float leaky(float x) { return fmaxf(x, 0.2f * x); }

// ---------------- Kernel A: e1[b,n] = h[b,n,:]·a1 ; e2[b,m] = g[b,m,:]·a2 ----
__global__ __launch_bounds__(256) void compute_e(
    const float* __restrict__ h, const float* __restrict__ g,
    const float* __restrict__ a1, const float* __restrict__ a2,
    float* __restrict__ e1, float* __restrict__ e2)
{
    int wave = (blockIdx.x * 256 + threadIdx.x) >> 6;
    int lane = threadIdx.x & 63;
    const float* src; const float* av; float* dst; int row = wave;
    if (wave < BB * NN) { src = h; av = a1; dst = e1; }
    else { row -= BB * NN; src = g; av = a2; dst = e2; }
    float2 x = *(const float2*)(src + (size_t)row * DD + lane * 2);
    float2 a = *(const float2*)(av + lane * 2);
    float p = x.x * a.x + x.y * a.y;
    #pragma unroll
    for (int s = 32; s; s >>= 1) p += __shfl_xor(p, s);
    if (lane == 0) dst[row] = p;
}

// ---------------- Kernel B: per-batch max of e2 ------------------------------
__global__ __launch_bounds__(256) void compute_e2max(
    const float* __restrict__ e2, float* __restrict__ e2max)
{
    int b = blockIdx.x, t = threadIdx.x;
    float m = -1e30f;
    for (int i = t; i < MM; i += 256) m = fmaxf(m, e2[b * MM + i]);
    #pragma unroll
    for (int s = 32; s; s >>= 1) m = fmaxf(m, __shfl_xor(m, s));
    __shared__ float sm[4];
    if ((t & 63) == 0) sm[t >> 6] = m;
    __syncthreads();
    if (t == 0) e2max[b] = fmaxf(fmaxf(sm[0], sm[1]), fmaxf(sm[2], sm[3]));
}

// ---------------- Kernel T: gbfT[b][d][m] = bf16(g[b][m][d]) -----------------
__global__ __launch_bounds__(256) void transpose_g(
    const float* __restrict__ g, ushort_t* __restrict__ gbfT)
{
    __shared__ ushort_t tl[DD][66];  // +2 pad breaks write bank conflicts
    int b = blockIdx.y, m0 = blockIdx.x * 64, t = threadIdx.x;
    #pragma unroll
    for (int i = 0; i < 8; i++) {
        int idx = i * 256 + t;
        int m = idx >> 5;            // 0..63
        int c4 = (idx & 31) * 4;     // d col 0..124
        float4 v = *(const float4*)(g + ((size_t)(b * MM + m0 + m)) * DD + c4);
        tl[c4 + 0][m] = (ushort_t)f2bf(v.x);
        tl[c4 + 1][m] = (ushort_t)f2bf(v.y);
        tl[c4 + 2][m] = (ushort_t)f2bf(v.z);
        tl[c4 + 3][m] = (ushort_t)f2bf(v.w);
    }
    __syncthreads();
    #pragma unroll
    for (int i = 0; i < 4; i++) {
        int idx = i * 256 + t;
        int d = idx >> 3;            // 0..127
        int c = (idx & 7) * 8;       // 0..56
        int4 o;
        o.x = (int)((unsigned)tl[d][c + 0] | ((unsigned)tl[d][c + 1] << 16));
        o.y = (int)((unsigned)tl[d][c + 2] | ((unsigned)tl[d][c + 3] << 16));
        o.z = (int)((unsigned)tl[d][c + 4] | ((unsigned)tl[d][c + 5] << 16));
        o.w = (int)((unsigned)tl[d][c + 6] | ((unsigned)tl[d][c + 7] << 16));
        *(int4*)(gbfT + ((size_t)(b * DD + d)) * MM + m0 + c) = o;
    }
}

// ---------------- Main: fused mask+softmax+PV --------------------------------
// block = 256 (4 waves); tile = 64 rows (n) x 64 cols (m) per chunk, 16 chunks.
// wave w owns output cols d0 = 32w..32w+31. w-tile in LDS, XOR-swizzled 16B chunks.
__global__ __launch_bounds__(256) void attn_main(
    const int* __restrict__ adj, const ushort_t* __restrict__ gbfT,
    const float* __restrict__ e1, const float* __restrict__ e2,
    const float* __restrict__ e2max, float* __restrict__ out)
{
    __shared__ int4 wt[64 * 8];      // 64 rows x 8 chunks of 8 bf16 (swizzled)
    __shared__ float scaleS[64];

    int b = blockIdx.y, n0 = blockIdx.x * 64;
    int t = threadIdx.x;
    int lane = t & 63, wid = t >> 6;
    int r = t >> 2, q = t & 3;       // w-compute: row r (0..63), col group q (16 cols)

    float e2m = e2max[b];
    float e1r = e1[b * NN + n0 + r];
    float Cr = leaky(e1r + e2m);     // >= every e in this row (leaky monotone)

    const int* aptr = adj + ((size_t)(b * NN + n0 + r)) * MM + q * 16;
    const float* eptr = e2 + b * MM + q * 16;
    const ushort_t* gb = gbfT + (size_t)b * DD * MM;
    int d0 = wid * 32;

    f32x4 zero = {0.f, 0.f, 0.f, 0.f};
    f32x4 acc[4][2];
    #pragma unroll
    for (int i = 0; i < 4; i++)
        for (int j = 0; j < 2; j++) acc[i][j] = zero;

    float zl = 0.f, dl = 0.f;

    int4 ca[4];
    #pragma unroll
    for (int i = 0; i < 4; i++) ca[i] = *(const int4*)(aptr + i * 4);

    for (int mc = 0; mc < 16; ++mc) {
        int4 na[4];
        if (mc < 15) {
            #pragma unroll
            for (int i = 0; i < 4; i++) na[i] = *(const int4*)(aptr + (mc + 1) * 64 + i * 4);
        }
        // compute w = adj ? exp(leaky(e1+e2) - C) : 0 for 16 elements
        float w[16];
        #pragma unroll
        for (int i = 0; i < 4; i++) {
            float4 ev = *(const float4*)(eptr + mc * 64 + i * 4);
            int   ax[4] = {ca[i].x, ca[i].y, ca[i].z, ca[i].w};
            float ex[4] = {ev.x, ev.y, ev.z, ev.w};
            #pragma unroll
            for (int jj = 0; jj < 4; jj++) {
                float s = e1r + ex[jj];
                float wv = (ax[jj] > 0) ? __expf(leaky(s) - Cr) : 0.f;
                w[i * 4 + jj] = wv;
                zl += wv;
                dl += (ax[jj] > 0) ? 1.f : 0.f;
            }
        }
        // pack to bf16, store to swizzled LDS (chunk ^= row&7 kills bank conflicts)
        int4 p0, p1;
        p0.x = (int)(f2bf(w[0])  | (f2bf(w[1])  << 16));
        p0.y = (int)(f2bf(w[2])  | (f2bf(w[3])  << 16));
        p0.z = (int)(f2bf(w[4])  | (f2bf(w[5])  << 16));
        p0.w = (int)(f2bf(w[6])  | (f2bf(w[7])  << 16));
        p1.x = (int)(f2bf(w[8])  | (f2bf(w[9])  << 16));
        p1.y = (int)(f2bf(w[10]) | (f2bf(w[11]) << 16));
        p1.z = (int)(f2bf(w[12]) | (f2bf(w[13]) << 16));
        p1.w = (int)(f2bf(w[14]) | (f2bf(w[15]) << 16));
        wt[r * 8 + ((2 * q)     ^ (r & 7))] = p0;
        wt[r * 8 + ((2 * q + 1) ^ (r & 7))] = p1;
        __syncthreads();

        // MFMA: A = w-tile (64x64, K=m), B = gbfT (K=m x 16 cols of d)
        #pragma unroll
        for (int ks = 0; ks < 2; ++ks) {
            bf16x8 af[4];
            #pragma unroll
            for (int i = 0; i < 4; i++) {
                int row = i * 16 + (lane & 15);
                af[i] = __builtin_bit_cast(bf16x8,
                        wt[row * 8 + (((ks * 4) + (lane >> 4)) ^ (row & 7))]);
            }
            #pragma unroll
            for (int j = 0; j < 2; j++) {
                const ushort_t* gp = gb + (size_t)(d0 + j * 16 + (lane & 15)) * MM
                                     + mc * 64 + ks * 32 + 8 * (lane >> 4);
                bf16x8 bfv = __builtin_bit_cast(bf16x8, *(const int4*)gp);
                #pragma unroll
                for (int i = 0; i < 4; i++)
                    acc[i][j] = __builtin_amdgcn_mfma_f32_16x16x32_bf16(
                                    af[i], bfv, acc[i][j], 0, 0, 0);
            }
        }
        __syncthreads();
        if (mc < 15) {
            #pragma unroll
            for (int i = 0; i < 4; i++) ca[i] = na[i];
        }
    }

    // reduce Z and deg across the 4 threads (q) of each row; scale = deg/Z
    zl += __shfl_xor(zl, 1); zl += __shfl_xor(zl, 2);
    dl += __shfl_xor(dl, 1); dl += __shfl_xor(dl, 2);
    if (q == 0) scaleS[r] = (dl > 0.f) ? (dl / zl) : 0.f;
    __syncthreads();

    // epilogue: D-layout row = 4*(lane>>4)+reg, col = lane&15
    float* ob = out + ((size_t)(b * NN + n0)) * DD + d0;
    #pragma unroll
    for (int i = 0; i < 4; i++)
        #pragma unroll
        for (int j = 0; j < 2; j++)
            #pragma unroll
            for (int rg = 0; rg < 4; rg++) {
                int row = i * 16 + 4 * (lane >> 4) + rg;
                ob[(size_t)row * DD + j * 16 + (lane & 15)] = acc[i][j][rg] * scaleS[row];
            }
}

extern "C" void kernel_launch(void* const* d_in, const int* in_sizes, int n_in,
                              void* d_out, int out_size, void* d_ws, size_t ws_size,
                              hipStream_t stream) {
    const float* h   = (const float*)d_in[0];
    const float* g   = (const float*)d_in[1];
    const int*   adj = (const int*)d_in[2];
    const float* a1  = (const float*)d_in[3];
    const float* a2  = (const float*)d_in[4];
    float* out = (float*)d_out;

    // workspace layout
    float* e1  = (float*)d_ws;                        // 32k floats
    float* e2  = e1 + BB * NN;                        // 32k floats
    float* e2m = e2 + BB * MM;                        // 32 floats
    ushort_t* gbfT = (ushort_t*)((char*)d_ws + (1u << 19));  // 8 MB

    compute_e<<<dim3((2 * BB * NN) / (256 / 64)), 256, 0, stream>>>(h, g, a1, a2, e1, e2);
    transpose_g<<<dim3(MM / 64, BB), 256, 0, stream>>>(g, gbfT);
    compute_e2max<<<dim3(BB), 256, 0, stream>>>(e2, e2m);
    attn_main<<<dim3(NN / 64, BB), 256, 0, stream>>>(adj, gbfT, e1, e2, e2m, out);
}